// Round 11
// baseline (691.088 us; speedup 1.0000x reference)
//
#include <hip/hip_runtime.h>

// Problem constants (B=2, H=16, L=2048, D=64 — fixed by the reference setup).
#define BH   32
#define LSEQ 2048
#define DDIM 64
#define ERRC 1e-12f

typedef __attribute__((ext_vector_type(8)))  short bf16x8;
typedef __attribute__((ext_vector_type(4)))  float floatx4;
typedef __attribute__((ext_vector_type(4)))  unsigned short ushort4v;

// float -> bf16 round-to-nearest-even (inputs are finite, no NaN handling needed)
__device__ __forceinline__ unsigned short f2bf(float f) {
    unsigned u = __float_as_uint(f);
    u = u + 0x7FFFu + ((u >> 16) & 1u);
    return (unsigned short)(u >> 16);
}

__device__ __forceinline__ bf16x8 pack8s(const float* __restrict__ p, float w) {
    const floatx4* pv = (const floatx4*)p;
    floatx4 x = pv[0], y = pv[1];
    bf16x8 r;
    r[0] = (short)f2bf(x[0] * w); r[1] = (short)f2bf(x[1] * w);
    r[2] = (short)f2bf(x[2] * w); r[3] = (short)f2bf(x[3] * w);
    r[4] = (short)f2bf(y[0] * w); r[5] = (short)f2bf(y[1] * w);
    r[6] = (short)f2bf(y[2] * w); r[7] = (short)f2bf(y[3] * w);
    return r;
}

// Prep: kd = bf16(k * sqrt(dest+err)) ONLY (8 MiB); ws = 9 MiB total.
__global__ __launch_bounds__(256) void prep_kd(const float* __restrict__ k,
                                               const float* __restrict__ dest,
                                               unsigned short* __restrict__ kd) {
    int idx4 = blockIdx.x * 256 + threadIdx.x;
    int row  = idx4 >> 4;                     // 16 float4 per 64-wide row
    float d = sqrtf(dest[row] + ERRC);
    floatx4 v = ((const floatx4*)k)[idx4];
    ushort4v od;
#pragma unroll
    for (int r = 0; r < 4; ++r) od[r] = f2bf(v[r] * d);
    ((ushort4v*)kd)[idx4] = od;
}

__device__ __forceinline__ void load_frag(const unsigned short* __restrict__ p,
                                          bf16x8& lo, bf16x8& hi) {
    lo = *(const bf16x8*)p;
    hi = *(const bf16x8*)(p + 32);
}

// B operand (ks row) computed on the fly from raw k + src — once per wave.
__device__ __forceinline__ void load_b_raw(const float* __restrict__ k,
                                           const float* __restrict__ src,
                                           int bhL, int row, int q,
                                           bf16x8& lo, bf16x8& hi) {
    const float* p = k + (long)(bhL + row) * DDIM + q * 8;
    float s = sqrtf(src[bhL + row] + ERRC);
    lo = pack8s(p, s);
    hi = pack8s(p + 32, s);
}

// ---------------------------------------------------------------------------
// Phase 1 (high-occupancy): 12288 INDEPENDENT waves, one per (bh, i-tile,
// strip cc=0..2). Each sums one 512-j strip for its 16 i-rows and writes
// S[row][cc]. __launch_bounds__(256,8): VGPR<=64, 8 waves/SIMD — no software
// prefetch (TLP hides L2 latency instead; frags fit the register cap).
// ---------------------------------------------------------------------------
__global__ __launch_bounds__(256, 8) void strip_sums2(const unsigned short* __restrict__ kd,
                                                      const float* __restrict__ k,
                                                      const float* __restrict__ src,
                                                      float* __restrict__ S) {
    const int tid  = threadIdx.x;
    const int wave = tid >> 6;
    const int lane = tid & 63;
    const int q    = lane >> 4;
    const int l16  = lane & 15;
    const int u    = blockIdx.x * 4 + wave;   // 0..12287
    const int bh   = u & 31;                  // low bits -> XCD mix
    const int rest = u >> 5;                  // 0..383
    const int it   = rest & 127;              // i-tile
    const int cc   = rest >> 7;               // 0..2 (strip)
    const int i0   = it << 4;
    const int bhL  = bh * LSEQ;
    const int jb   = cc << 9;
    const unsigned short* kdb = kd + (long)bh * LSEQ * DDIM;

    bf16x8 blo, bhi;
    load_b_raw(k, src, bhL, i0 + l16, q, blo, bhi);

    const float c23 = 2.0f / 3.0f;
    float ss = 0.f;

    for (int g = 0; g < 8; ++g) {
        const int j0 = jb + (g << 6);
        bf16x8 aLo[4], aHi[4];
#pragma unroll
        for (int t = 0; t < 4; ++t)
            load_frag(kdb + (long)(j0 + 16 * t + l16) * DDIM + q * 8, aLo[t], aHi[t]);

#pragma unroll
        for (int t = 0; t < 4; ++t) {
            floatx4 z4 = {0.f, 0.f, 0.f, 0.f};
            z4 = __builtin_amdgcn_mfma_f32_16x16x32_bf16(aLo[t], blo, z4, 0, 0, 0);
            floatx4 acc = __builtin_amdgcn_mfma_f32_16x16x32_bf16(aHi[t], bhi, z4, 0, 0, 0);
#pragma unroll
            for (int r = 0; r < 4; ++r) {
                float v = fmaxf(acc[r], 0.f) + ERRC;
                ss += exp2f(c23 * __log2f(v));
            }
        }
    }
    // cross-quad reduce once at the end (sum is associative across groups)
    float s1 = ss + __shfl_xor(ss, 16, 64);
    ss = s1 + __shfl_xor(s1, 32, 64);
    if (q == 0)
        S[(long)(bhL + i0 + l16) * 4 + cc] = ss;
}

// ---------------------------------------------------------------------------
// Phase 2 (high-occupancy): 16384 INDEPENDENT waves, one per (bh, i-tile,
// chunk c=0..3). Carry seeded from the strip-sum prefix. Direct cached
// floatx4 stores (store shape proven irrelevant, rounds 3-10). No prefetch;
// __launch_bounds__(256,8) for 8 waves/SIMD.
// Scan/store logic lifted verbatim from round-9's chunk_out2 (harness-passed).
// ---------------------------------------------------------------------------
__global__ __launch_bounds__(256, 8) void chunk_out3(const unsigned short* __restrict__ kd,
                                                     const float* __restrict__ k,
                                                     const float* __restrict__ src,
                                                     const float* __restrict__ S,
                                                     float* __restrict__ out) {
    const int tid  = threadIdx.x;
    const int wave = tid >> 6;
    const int lane = tid & 63;
    const int q    = lane >> 4;
    const int l16  = lane & 15;
    const int u    = blockIdx.x * 4 + wave;   // 0..16383
    const int bh   = u & 31;                  // low bits -> XCD mix
    const int rest = u >> 5;                  // 0..511
    const int it   = rest & 127;              // i-tile
    const int c    = rest >> 7;               // 0..3 (chunk, high bits like r8)
    const int i0   = it << 4;
    const int bhL  = bh * LSEQ;
    const int jb   = c << 9;                  // chunk base (512 cols)

    if (jb + 512 <= i0) {
        // fully masked chunk: zero-fill, 1KB contiguous per instruction
        const floatx4 z = {0.f, 0.f, 0.f, 0.f};
#pragma unroll
        for (int s = 0; s < 16; ++s) {
            float* row = out + (long)(bhL + i0 + s) * LSEQ + jb + 4 * lane;
            *(floatx4*)row = z;
            *(floatx4*)(row + 256) = z;
        }
        return;
    }

    const unsigned short* kdb = kd + (long)bh * LSEQ * DDIM;

    bf16x8 blo, bhi;
    load_b_raw(k, src, bhL, i0 + l16, q, blo, bhi);

    // starting carry for row i0+l16 = sum of preceding strip sums
    float carry = 0.f;
    const float* Sr = S + (long)(bhL + i0 + l16) * 4;
#pragma unroll
    for (int cc = 0; cc < 3; ++cc)
        if (cc < c) carry += Sr[cc];

    const float c23 = 2.0f / 3.0f;
    float* orow = out + (long)(bhL + i0 + l16) * LSEQ + q * 4;

    for (int g = 0; g < 8; ++g) {
        const int j0 = jb + (g << 6);

        bf16x8 aLo[4], aHi[4];
#pragma unroll
        for (int t = 0; t < 4; ++t)
            load_frag(kdb + (long)(j0 + 16 * t + l16) * DDIM + q * 8, aLo[t], aHi[t]);

        floatx4 acc[4];
#pragma unroll
        for (int t = 0; t < 4; ++t) {
            floatx4 z4 = {0.f, 0.f, 0.f, 0.f};
            z4 = __builtin_amdgcn_mfma_f32_16x16x32_bf16(aLo[t], blo, z4, 0, 0, 0);
            acc[t] = __builtin_amdgcn_mfma_f32_16x16x32_bf16(aHi[t], bhi, z4, 0, 0, 0);
        }

        float uu[4][4];
#pragma unroll
        for (int t = 0; t < 4; ++t)
#pragma unroll
            for (int r = 0; r < 4; ++r) {
                float v = fmaxf(acc[t][r], 0.f) + ERRC;
                uu[t][r] = exp2f(c23 * __log2f(v));
            }

        if (j0 + 64 <= i0) {
            // fully masked group: only the total feeds the carry; store zeros
            float s = 0.f;
#pragma unroll
            for (int t = 0; t < 4; ++t)
                s += (uu[t][0] + uu[t][1]) + (uu[t][2] + uu[t][3]);
            float s1 = s + __shfl_xor(s, 16, 64);
            carry += s1 + __shfl_xor(s1, 32, 64);
            const floatx4 z = {0.f, 0.f, 0.f, 0.f};
#pragma unroll
            for (int t = 0; t < 4; ++t)
                *(floatx4*)(orow + j0 + 16 * t) = z;
        } else {
#pragma unroll
            for (int t = 0; t < 4; ++t) {
                const int jt0 = j0 + 16 * t;
                if (jt0 + 16 <= i0) {
                    float s = (uu[t][0] + uu[t][1]) + (uu[t][2] + uu[t][3]);
                    float s1 = s + __shfl_xor(s, 16, 64);
                    carry += s1 + __shfl_xor(s1, 32, 64);
                    const floatx4 z = {0.f, 0.f, 0.f, 0.f};
                    *(floatx4*)(orow + jt0) = z;
                } else {
                    // in-lane inclusive prefix over this lane's 4 consecutive j
                    uu[t][1] += uu[t][0];
                    uu[t][2] += uu[t][1];
                    uu[t][3] += uu[t][2];
                    const float Sg  = uu[t][3];
                    const float x16 = __shfl_xor(Sg, 16, 64);
                    const float s1  = Sg + x16;
                    const float x32 = __shfl_xor(s1, 32, 64);
                    const float E = ((q & 1) ? x16 : 0.f) + ((q & 2) ? x32 : 0.f) + carry;
                    carry += s1 + x32;
                    floatx4 o;
                    if (jt0 == i0) {          // the single mixed (diagonal) tile
#pragma unroll
                        for (int r = 0; r < 4; ++r)
                            o[r] = ((q * 4 + r) >= l16) ? (uu[t][r] + E) : 0.f;
                    } else {                  // fully above diagonal
#pragma unroll
                        for (int r = 0; r < 4; ++r)
                            o[r] = uu[t][r] + E;
                    }
                    *(floatx4*)(orow + jt0) = o;
                }
            }
        }
    }
}

// ---------------------------------------------------------------------------
// Fallback (workspace too small): single-pass kernel reading raw fp32 k
// (round-3 structure, harness-proven). Correct but slower.
// ---------------------------------------------------------------------------
__device__ __forceinline__ void load_row16_raw(const float* __restrict__ kp, long base, int row,
                                               int q, const float* __restrict__ w, int bhL,
                                               bf16x8& lo, bf16x8& hi) {
    const float* p = kp + base + (long)row * DDIM + q * 8;
    float s = sqrtf(w[bhL + row] + ERRC);
    lo = pack8s(p, s);
    hi = pack8s(p + 32, s);
}

__global__ __launch_bounds__(256, 4) void mha_raw(const float* __restrict__ kp,
                                                  const float* __restrict__ src,
                                                  const float* __restrict__ dest,
                                                  float* __restrict__ out) {
    const int tid  = threadIdx.x;
    const int wave = tid >> 6;
    const int lane = tid & 63;
    const int q    = lane >> 4;
    const int l16  = lane & 15;
    const int bh = blockIdx.x & 31;
    const int ib = blockIdx.x >> 5;
    const int i0 = (ib * 4 + wave) * 16;
    const int bhL = bh * LSEQ;
    const long base = (long)bh * LSEQ * DDIM;

    bf16x8 blo, bhi;
    load_row16_raw(kp, base, i0 + l16, q, src, bhL, blo, bhi);

    float carry = 0.f;
    const float c23 = 2.0f / 3.0f;

    bf16x8 aLo[4], aHi[4];
#pragma unroll
    for (int t = 0; t < 4; ++t)
        load_row16_raw(kp, base, 16 * t + l16, q, dest, bhL, aLo[t], aHi[t]);

    float* orow = out + (long)(bhL + i0 + l16) * LSEQ + q * 4;

    for (int it = 0; it < 32; ++it) {
        const int j0 = it << 6;
        bf16x8 nLo[4], nHi[4];
        const int jn = (it < 31) ? (j0 + 64) : 0;
#pragma unroll
        for (int t = 0; t < 4; ++t)
            load_row16_raw(kp, base, jn + 16 * t + l16, q, dest, bhL, nLo[t], nHi[t]);

        floatx4 acc[4];
#pragma unroll
        for (int t = 0; t < 4; ++t) {
            floatx4 z4 = {0.f, 0.f, 0.f, 0.f};
            z4 = __builtin_amdgcn_mfma_f32_16x16x32_bf16(aLo[t], blo, z4, 0, 0, 0);
            acc[t] = __builtin_amdgcn_mfma_f32_16x16x32_bf16(aHi[t], bhi, z4, 0, 0, 0);
        }

        float uu[4][4];
#pragma unroll
        for (int t = 0; t < 4; ++t)
#pragma unroll
            for (int r = 0; r < 4; ++r) {
                float v = fmaxf(acc[t][r], 0.f) + ERRC;
                uu[t][r] = exp2f(c23 * __log2f(v));
            }

#pragma unroll
        for (int t = 0; t < 4; ++t) {
            const int jt0 = j0 + 16 * t;
            if (jt0 + 16 <= i0) {
                float s = (uu[t][0] + uu[t][1]) + (uu[t][2] + uu[t][3]);
                float s1 = s + __shfl_xor(s, 16, 64);
                carry += s1 + __shfl_xor(s1, 32, 64);
                const floatx4 z = {0.f, 0.f, 0.f, 0.f};
                *(floatx4*)(orow + jt0) = z;
            } else {
                uu[t][1] += uu[t][0];
                uu[t][2] += uu[t][1];
                uu[t][3] += uu[t][2];
                const float Sg  = uu[t][3];
                const float x16 = __shfl_xor(Sg, 16, 64);
                const float s1  = Sg + x16;
                const float x32 = __shfl_xor(s1, 32, 64);
                const float E = ((q & 1) ? x16 : 0.f) + ((q & 2) ? x32 : 0.f) + carry;
                carry += s1 + x32;
                floatx4 o;
                if (jt0 == i0) {
#pragma unroll
                    for (int r = 0; r < 4; ++r)
                        o[r] = ((q * 4 + r) >= l16) ? (uu[t][r] + E) : 0.f;
                } else {
#pragma unroll
                    for (int r = 0; r < 4; ++r)
                        o[r] = uu[t][r] + E;
                }
                *(floatx4*)(orow + jt0) = o;
            }
        }

#pragma unroll
        for (int t = 0; t < 4; ++t) { aLo[t] = nLo[t]; aHi[t] = nHi[t]; }
    }
}

extern "C" void kernel_launch(void* const* d_in, const int* in_sizes, int n_in,
                              void* d_out, int out_size, void* d_ws, size_t ws_size,
                              hipStream_t stream) {
    const float* k    = (const float*)d_in[0];
    const float* src  = (const float*)d_in[1];
    const float* dest = (const float*)d_in[2];
    float* out = (float*)d_out;

    const size_t kdsz = (size_t)BH * LSEQ * DDIM * sizeof(unsigned short); // 8 MiB
    const size_t ssz  = (size_t)BH * LSEQ * 4 * sizeof(float);             // 1 MiB
    if (ws_size >= kdsz + ssz) {                                           // 9 MiB total
        unsigned short* kd = (unsigned short*)d_ws;
        float* S = (float*)((char*)d_ws + kdsz);
        prep_kd<<<dim3(4096), dim3(256), 0, stream>>>(k, dest, kd);
        strip_sums2<<<dim3(3072), dim3(256), 0, stream>>>(kd, k, src, S);
        chunk_out3<<<dim3(4096), dim3(256), 0, stream>>>(kd, k, src, S, out);
    } else {
        mha_raw<<<dim3(1024), dim3(256), 0, stream>>>(k, src, dest, out);
    }
}

// Round 12
// 583.334 us; speedup vs baseline: 1.1847x; 1.1847x over previous
//
#include <hip/hip_runtime.h>

// Problem constants (B=2, H=16, L=2048, D=64 — fixed by the reference setup).
#define BH   32
#define LSEQ 2048
#define DDIM 64
#define ERRC 1e-12f
#define SROW 129   // LDS strip row stride in floats (128 cols + 1 pad) — round-4 proven

typedef __attribute__((ext_vector_type(8)))  short bf16x8;
typedef __attribute__((ext_vector_type(4)))  float floatx4;
typedef __attribute__((ext_vector_type(4)))  unsigned short ushort4v;

// float -> bf16 round-to-nearest-even (inputs are finite, no NaN handling needed)
__device__ __forceinline__ unsigned short f2bf(float f) {
    unsigned u = __float_as_uint(f);
    u = u + 0x7FFFu + ((u >> 16) & 1u);
    return (unsigned short)(u >> 16);
}

__device__ __forceinline__ bf16x8 pack8s(const float* __restrict__ p, float w) {
    const floatx4* pv = (const floatx4*)p;
    floatx4 x = pv[0], y = pv[1];
    bf16x8 r;
    r[0] = (short)f2bf(x[0] * w); r[1] = (short)f2bf(x[1] * w);
    r[2] = (short)f2bf(x[2] * w); r[3] = (short)f2bf(x[3] * w);
    r[4] = (short)f2bf(y[0] * w); r[5] = (short)f2bf(y[1] * w);
    r[6] = (short)f2bf(y[2] * w); r[7] = (short)f2bf(y[3] * w);
    return r;
}

// Prep: ks = bf16(k*sqrt(src+err)) row-major (B operand, read once per wave);
//       kd = bf16(k*sqrt(dest+err)) in MFMA-TILE layout: tile jt (16 rows) is
//       1024 contiguous ush; lane ln's lo-fragment at jt*1024 + ln*8, hi at
//       +512. One tile load = two coalesced 1KB instructions (8 full cache
//       lines) instead of 16 half-line scatters — 4x fewer L2 requests.
__global__ __launch_bounds__(256) void prep_scaled2(const float* __restrict__ k,
                                                    const float* __restrict__ src,
                                                    const float* __restrict__ dest,
                                                    unsigned short* __restrict__ ks,
                                                    unsigned short* __restrict__ kd) {
    int idx4 = blockIdx.x * 256 + threadIdx.x;
    int row  = idx4 >> 4;                     // global row: bh*2048 + r
    int d    = (idx4 & 15) * 4;               // element offset 0..60
    float s = sqrtf(src[row] + ERRC);
    float dd = sqrtf(dest[row] + ERRC);
    floatx4 v = ((const floatx4*)k)[idx4];
    ushort4v os, od;
#pragma unroll
    for (int r = 0; r < 4; ++r) { os[r] = f2bf(v[r] * s); od[r] = f2bf(v[r] * dd); }
    ((ushort4v*)ks)[idx4] = os;               // row-major
    // tiled kd: (row,d) -> tile (row>>4), half (d>=32), lane q*16+l16, slot d&7
    const int jt   = row >> 4;                // global tile (bh*128 + local)
    const int l16  = row & 15;
    const int half = d >> 5;
    const int q    = (d & 31) >> 3;
    const long off = (long)jt * 1024 + half * 512 + (q * 16 + l16) * 8 + (d & 7);
    *(ushort4v*)(kd + off) = od;
}

// A-operand tile load. TILED: two coalesced 1KB loads. RAW: r4's on-the-fly
// pack from fp32 k (16-row scatter — fallback only).
template<bool RAW>
__device__ __forceinline__ void load_a(const void* __restrict__ ka,
                                       const float* __restrict__ dest,
                                       int bh, int jbase, int t,
                                       int lane, int q, int l16,
                                       bf16x8& lo, bf16x8& hi) {
    if (RAW) {
        const float* kp = (const float*)ka;
        const int row = jbase + 16 * t + l16;
        const float* p = kp + (long)(bh * LSEQ + row) * DDIM + q * 8;
        float s = sqrtf(dest[bh * LSEQ + row] + ERRC);
        lo = pack8s(p, s);
        hi = pack8s(p + 32, s);
    } else {
        const unsigned short* kdb = (const unsigned short*)ka + (long)bh * (128 * 1024);
        const unsigned short* tb = kdb + (long)((jbase >> 4) + t) * 1024 + lane * 8;
        lo = *(const bf16x8*)tb;
        hi = *(const bf16x8*)(tb + 512);
    }
}

// B operand: ks row i0+l16 (row-major prep) or on-the-fly pack from raw k.
template<bool RAW>
__device__ __forceinline__ void load_b(const void* __restrict__ kb,
                                       const float* __restrict__ src,
                                       int bh, int row, int q,
                                       bf16x8& lo, bf16x8& hi) {
    if (RAW) {
        const float* p = (const float*)kb + (long)(bh * LSEQ + row) * DDIM + q * 8;
        float s = sqrtf(src[bh * LSEQ + row] + ERRC);
        lo = pack8s(p, s);
        hi = pack8s(p + 32, s);
    } else {
        const unsigned short* p = (const unsigned short*)kb + (long)(bh * LSEQ + row) * DDIM + q * 8;
        lo = *(const bf16x8*)p;
        hi = *(const bf16x8*)(p + 32);
    }
}

// Round-4 kernel (613 µs best) with ONE change: A-operand loads read the
// tile-contiguous kd layout (coalesced 1KB instructions, 4x fewer L2 reqs).
// One wave = one 16-column i-tile; streams 32 groups of 64 j (4 16-row tiles),
// staging each 16x128 output strip in wave-private LDS, then flushing with
// 8 stores of 2 rows x 512B contiguous.
// Swapped MFMA: D = kd_tile(j rows) . ks_rows(i)^T -> D[m=j][n=i],
// C/D: col(l16)=i, row(q*4+r)=j -> each lane holds 4 CONSECUTIVE j per tile.
template<bool RAW>
__global__ __launch_bounds__(256, 4) void mha_fused8(const void* __restrict__ ka,  // kd tiled (or raw k)
                                                     const void* __restrict__ kb,  // ks (or raw k)
                                                     const float* __restrict__ src,
                                                     const float* __restrict__ dest,
                                                     float* __restrict__ out) {
    __shared__ float strip[4][16 * SROW];     // 8.25 KiB per wave, wave-private (no barriers)
    const int tid  = threadIdx.x;
    const int wave = tid >> 6;
    const int lane = tid & 63;
    const int q    = lane >> 4;
    const int l16  = lane & 15;
    // bh in low bits: same-bh blocks are 32 apart -> same XCD under mod-8 dispatch.
    const int bh = blockIdx.x & 31;
    const int ib = blockIdx.x >> 5;           // 0..31
    const int i0 = (ib * 4 + wave) * 16;      // this wave's 16-column (i) tile
    const int bhL = bh * LSEQ;
    float* sw = strip[wave];

    // B operand: ks row i0+l16, held for the whole kernel
    bf16x8 blo, bhi;
    load_b<RAW>(kb, src, bh, i0 + l16, q, blo, bhi);

    float carry = 0.f;                        // running row sum for output row i0+l16
    const float c23 = 2.0f / 3.0f;

    // prefetch j-tiles 0..3
    bf16x8 aLo[4], aHi[4];
#pragma unroll
    for (int t = 0; t < 4; ++t)
        load_a<RAW>(ka, dest, bh, 0, t, lane, q, l16, aLo[t], aHi[t]);

    // flush mapping: lanes 0..31 -> row 2s, lanes 32..63 -> row 2s+1; 4 cols/lane
    const int h2  = lane >> 5;
    const int c32 = lane & 31;
    float* obase = out + (long)(bhL + i0 + h2) * LSEQ + 4 * c32;
    const int lrd = h2 * SROW + 4 * c32;

    for (int sup = 0; sup < 16; ++sup) {
        const int j0s = sup << 7;             // strip base (128 cols)
        const bool maskedStrip = (j0s + 128) <= i0;

#pragma unroll
        for (int half = 0; half < 2; ++half) {
            const int j0 = j0s + (half << 6);
            const int colbase = half << 6;

            // prefetch next group's 4 tiles (redundant reload of tiles 0..3 at the end)
            bf16x8 nLo[4], nHi[4];
            const int jn = (j0 + 64 < LSEQ) ? (j0 + 64) : 0;
#pragma unroll
            for (int t = 0; t < 4; ++t)
                load_a<RAW>(ka, dest, bh, jn, t, lane, q, l16, nLo[t], nHi[t]);

            // 8 MFMAs, independent across the 4 tiles
            floatx4 acc[4];
#pragma unroll
            for (int t = 0; t < 4; ++t) {
                floatx4 z4 = {0.f, 0.f, 0.f, 0.f};
                z4 = __builtin_amdgcn_mfma_f32_16x16x32_bf16(aLo[t], blo, z4, 0, 0, 0);
                acc[t] = __builtin_amdgcn_mfma_f32_16x16x32_bf16(aHi[t], bhi, z4, 0, 0, 0);
            }

            // a3 = exp2(log2(relu(a1)+err) * 2/3) — 16 independent elements
            float u[4][4];
#pragma unroll
            for (int t = 0; t < 4; ++t)
#pragma unroll
                for (int r = 0; r < 4; ++r) {
                    float v = fmaxf(acc[t][r], 0.f) + ERRC;
                    u[t][r] = exp2f(c23 * __log2f(v));
                }

            if (j0 + 64 <= i0) {
                // all 4 tiles fully below the diagonal: only the total feeds carry
                float s = 0.f;
#pragma unroll
                for (int t = 0; t < 4; ++t)
                    s += (u[t][0] + u[t][1]) + (u[t][2] + u[t][3]);
                float s1 = s + __shfl_xor(s, 16, 64);
                carry += s1 + __shfl_xor(s1, 32, 64);
                if (!maskedStrip) {           // mixed strip: stage the zeros for the flush
                    const floatx4 z = {0.f, 0.f, 0.f, 0.f};
#pragma unroll
                    for (int t = 0; t < 4; ++t)
                        *(floatx4*)&sw[l16 * SROW + colbase + 16 * t + 4 * q] = z;
                }
            } else {
#pragma unroll
                for (int t = 0; t < 4; ++t) {
                    const int jt0 = j0 + 16 * t;
                    float* dst = &sw[l16 * SROW + colbase + 16 * t + 4 * q];
                    if (jt0 + 16 <= i0) {
                        // fully masked tile: total only
                        float s = (u[t][0] + u[t][1]) + (u[t][2] + u[t][3]);
                        float s1 = s + __shfl_xor(s, 16, 64);
                        carry += s1 + __shfl_xor(s1, 32, 64);
                        const floatx4 z = {0.f, 0.f, 0.f, 0.f};
                        *(floatx4*)dst = z;
                    } else {
                        // in-lane inclusive prefix over this lane's 4 consecutive j
                        u[t][1] += u[t][0];
                        u[t][2] += u[t][1];
                        u[t][3] += u[t][2];
                        const float S   = u[t][3];
                        const float x16 = __shfl_xor(S, 16, 64);
                        const float s1  = S + x16;
                        const float x32 = __shfl_xor(s1, 32, 64);
                        // exclusive prefix over the 4 q-chunks + running carry
                        const float E = ((q & 1) ? x16 : 0.f) + ((q & 2) ? x32 : 0.f) + carry;
                        carry += s1 + x32;    // tile total — identical across the group
                        floatx4 o;
                        if (jt0 == i0) {      // the single mixed (diagonal) tile
#pragma unroll
                            for (int r = 0; r < 4; ++r)
                                o[r] = ((q * 4 + r) >= l16) ? (u[t][r] + E) : 0.f;
                        } else {              // fully above diagonal
#pragma unroll
                            for (int r = 0; r < 4; ++r)
                                o[r] = u[t][r] + E;
                        }
                        *(floatx4*)dst = o;
                    }
                }
            }

#pragma unroll
            for (int t = 0; t < 4; ++t) { aLo[t] = nLo[t]; aHi[t] = nHi[t]; }
        }

        // Flush the 16x128 strip: 8 instrs, each 2 rows x 512B contiguous (full lines).
        float* og = obase + j0s;
        if (maskedStrip) {
            const floatx4 z = {0.f, 0.f, 0.f, 0.f};
#pragma unroll
            for (int s = 0; s < 8; ++s)
                *(floatx4*)(og + (long)(2 * s) * LSEQ) = z;
        } else {
#pragma unroll
            for (int s = 0; s < 8; ++s) {
                floatx4 v = *(const floatx4*)&sw[lrd + 2 * s * SROW];
                *(floatx4*)(og + (long)(2 * s) * LSEQ) = v;
            }
        }
    }
}

extern "C" void kernel_launch(void* const* d_in, const int* in_sizes, int n_in,
                              void* d_out, int out_size, void* d_ws, size_t ws_size,
                              hipStream_t stream) {
    const float* k    = (const float*)d_in[0];
    const float* src  = (const float*)d_in[1];
    const float* dest = (const float*)d_in[2];
    float* out = (float*)d_out;

    const size_t half = (size_t)BH * LSEQ * DDIM * sizeof(unsigned short); // 8 MiB
    if (ws_size >= 2 * half) {
        unsigned short* ks = (unsigned short*)d_ws;
        unsigned short* kd = (unsigned short*)((char*)d_ws + half);        // tiled layout
        prep_scaled2<<<dim3(4096), dim3(256), 0, stream>>>(k, src, dest, ks, kd);
        mha_fused8<false><<<dim3(1024), dim3(256), 0, stream>>>(kd, ks, src, dest, out);
    } else {
        mha_fused8<true><<<dim3(1024), dim3(256), 0, stream>>>(k, k, src, dest, out);
    }
}